// Round 17
// baseline (256.848 us; speedup 1.0000x reference)
//
#include <hip/hip_runtime.h>

#define LN_EPS 1e-5f
#define NBLK 512            // blocks for bucket hist/scatter passes
#define BSH  7              // 128 nodes per bucket
#define MAXB 512            // max buckets (N <= 65536)

typedef __attribute__((ext_vector_type(8))) short bf16x8;   // 8 bf16 = 4 VGPR (MFMA A/B frag)
typedef __attribute__((ext_vector_type(4))) float f32x4;    // MFMA C/D frag

#define MFMA_B16(a, b, c) __builtin_amdgcn_mfma_f32_16x16x32_bf16((a), (b), (c), 0, 0, 0)

__device__ __forceinline__ float bflo(unsigned int u) {
  return __builtin_bit_cast(float, u << 16);
}
__device__ __forceinline__ float bfhi(unsigned int u) {
  return __builtin_bit_cast(float, u & 0xffff0000u);
}
__device__ __forceinline__ float bfs(unsigned short u) {    // single bf16 -> f32
  return __builtin_bit_cast(float, (unsigned int)u << 16);
}
__device__ __forceinline__ unsigned short f2bf(float f) {   // f32 -> bf16 RNE
  unsigned int u = __builtin_bit_cast(unsigned int, f);
  u += 0x7fffu + ((u >> 16) & 1u);
  return (unsigned short)(u >> 16);
}
__device__ __forceinline__ float degrs(int d) { return rsqrtf((float)max(d, 1)); }

// All node-feature buffers (featb, aggb, zb, agg2z) use SLICE-MAJOR layout:
//   buf[slice][node][32 cols], slice = col >> 5, stride SL = N*32 elements.
// A 3.2 MB slice fits a 4 MB per-XCD L2; gathers run slice-phased.

// ---- A: per-block bucket histograms (dst and src), no global atomics -------------
__global__ __launch_bounds__(256)
void bucket_hist(const int* __restrict__ src, const int* __restrict__ dst,
                 int* __restrict__ blk_cnt, int E, int nbk) {
  __shared__ int h[2 * MAXB];
  int b = blockIdx.x, t = threadIdx.x;
  for (int i = t; i < nbk; i += 256) { h[i] = 0; h[MAXB + i] = 0; }
  __syncthreads();
  int chunk = (E + NBLK - 1) / NBLK;
  int beg = b * chunk, end = min(E, beg + chunk);
  for (int i = beg + t; i < end; i += 256) {
    atomicAdd(&h[dst[i] >> BSH], 1);
    atomicAdd(&h[MAXB + (src[i] >> BSH)], 1);
  }
  __syncthreads();
  for (int i = t; i < nbk; i += 256) {
    blk_cnt[(size_t)i * NBLK + b] = h[i];
    blk_cnt[(size_t)(nbk + i) * NBLK + b] = h[MAXB + i];
  }
}

// ---- generic hierarchical exclusive scan (partial + final), for boff --------------
__global__ __launch_bounds__(256)
void scan_partial_g(const int* __restrict__ v, int* __restrict__ part, int L) {
  __shared__ int sd[256];
  int base = blockIdx.x * 1024;
  int t = threadIdx.x;
  int s = 0;
#pragma unroll
  for (int i = 0; i < 4; ++i) { int idx = base + t * 4 + i; if (idx < L) s += v[idx]; }
  sd[t] = s; __syncthreads();
  for (int o = 128; o > 0; o >>= 1) { if (t < o) sd[t] += sd[t + o]; __syncthreads(); }
  if (t == 0) part[blockIdx.x] = sd[0];
}

__global__ __launch_bounds__(256)
void scan_final_g(const int* __restrict__ v, const int* __restrict__ part,
                  int* __restrict__ off, int L) {
  __shared__ int sd[256];
  __shared__ int pex_s;
  int base = blockIdx.x * 1024;
  int t = threadIdx.x;
  if (t < 64) {
    int p = 0;
    for (int i = t; i < (int)blockIdx.x; i += 64) p += part[i];
#pragma unroll
    for (int o = 1; o < 64; o <<= 1) p += __shfl_xor(p, o, 64);
    if (t == 0) pex_s = p;
  }
  int loc[4]; int s = 0;
#pragma unroll
  for (int i = 0; i < 4; ++i) {
    int idx = base + t * 4 + i;
    loc[i] = (idx < L) ? v[idx] : 0;
    s += loc[i];
  }
  sd[t] = s; __syncthreads();
  for (int o = 1; o < 256; o <<= 1) {
    int x = (t >= o) ? sd[t - o] : 0;
    __syncthreads();
    sd[t] += x;
    __syncthreads();
  }
  int excl = sd[t] - s + pex_s;
#pragma unroll
  for (int i = 0; i < 4; ++i) {
    int idx = base + t * 4 + i;
    if (idx < L) off[idx] = excl;
    excl += loc[i];
  }
}

// ---- C: bucket-partition edges; LDS cursors; writes bucket-contiguous regions -----
__global__ __launch_bounds__(256)
void bucket_scatter(const int* __restrict__ src, const int* __restrict__ dst,
                    const int* __restrict__ off, unsigned int* __restrict__ pairs,
                    int E, int nbk) {
  __shared__ int cur[2 * MAXB];
  int b = blockIdx.x, t = threadIdx.x;
  for (int i = t; i < nbk; i += 256) {
    cur[i] = off[(size_t)i * NBLK + b];
    cur[MAXB + i] = off[(size_t)(nbk + i) * NBLK + b];
  }
  __syncthreads();
  int chunk = (E + NBLK - 1) / NBLK;
  int beg = b * chunk, end = min(E, beg + chunk);
  for (int i = beg + t; i < end; i += 256) {
    int d = dst[i], s = src[i];
    int p1 = atomicAdd(&cur[d >> BSH], 1);
    pairs[p1] = ((unsigned int)s << BSH) | (unsigned int)(d & 127);
    int p2 = atomicAdd(&cur[MAXB + (s >> BSH)], 1);
    pairs[p2] = (unsigned int)(s & 127);
  }
}

// ---- bucket_finish: dst buckets do hist+scan+row_off+deg_d AND csr fill; src
// buckets write deg_s. NO converts here (R13's cross-block race lesson).
__global__ __launch_bounds__(256)
void bucket_finish(const unsigned int* __restrict__ pairs, const int* __restrict__ off,
                   int* __restrict__ row_off, int* __restrict__ deg_d,
                   int* __restrict__ deg_s, int* __restrict__ csr_src,
                   int N, int E, int nbk) {
  __shared__ int h[128];
  __shared__ int cur[128];
  int g = blockIdx.x, t = threadIdx.x;
  if (t < 128) h[t] = 0;
  __syncthreads();
  if (g < nbk) {
    int base = off[(size_t)g * NBLK];
    int end  = off[(size_t)(g + 1) * NBLK];     // g==nbk-1 -> start of src region == E
    for (int i = base + t; i < end; i += 256) atomicAdd(&h[pairs[i] & 127], 1);
    __syncthreads();
    int orig = (t < 128) ? h[t] : 0;
    for (int o = 1; o < 128; o <<= 1) {          // Hillis-Steele inclusive scan
      int v = (t < 128 && t >= o) ? h[t - o] : 0;
      __syncthreads();
      if (t < 128) h[t] += v;
      __syncthreads();
    }
    if (t < 128) {
      int excl = base + h[t] - orig;
      cur[t] = excl;
      int node = (g << BSH) + t;
      if (node < N) { row_off[node] = excl; deg_d[node] = orig; }
    }
    if (g == nbk - 1 && t == 0) row_off[N] = E;
    __syncthreads();
    for (int i = base + t; i < end; i += 256) {
      unsigned int v = pairs[i];
      int pos = atomicAdd(&cur[v & 127], 1);
      csr_src[pos] = (int)(v >> BSH);
    }
  } else {
    int j = g - nbk;
    int beg = off[(size_t)(nbk + j) * NBLK];
    int end = (j + 1 < nbk) ? off[(size_t)(nbk + j + 1) * NBLK] : 2 * E;
    for (int i = beg + t; i < end; i += 256) atomicAdd(&h[pairs[i] & 127], 1);
    __syncthreads();
    int nb0 = j << BSH;
    if (t < 128 && nb0 + t < N) deg_s[nb0 + t] = h[t];
  }
}

// ---- convert_all: featb(sliced) = bf16(x*rs_out) + 6 weight transposes ------------
__global__ __launch_bounds__(256)
void convert_all(const float* __restrict__ x, const int* __restrict__ deg_s,
                 unsigned short* __restrict__ xb, int n4, size_t SL,
                 const float* __restrict__ W1a, const float* __restrict__ W1b,
                 const float* __restrict__ W2a, const float* __restrict__ W2b,
                 const float* __restrict__ Wf1, const float* __restrict__ Wf2,
                 unsigned short* __restrict__ w1aT, unsigned short* __restrict__ w1bT,
                 unsigned short* __restrict__ w2aT, unsigned short* __restrict__ w2bT,
                 unsigned short* __restrict__ wf1T, unsigned short* __restrict__ wf2T) {
  const int featB = (n4 + 255) >> 8;
  int b = blockIdx.x, t = threadIdx.x;
  if (b < featB) {
    int i = b * 256 + t;
    if (i < n4) {
      int node = i >> 5, c = i & 31;            // 4-float chunk c of node's 128 cols
      float sc = degrs(deg_s[node]);
      float4 v = reinterpret_cast<const float4*>(x)[i];
      ushort4 r;
      r.x = f2bf(v.x * sc); r.y = f2bf(v.y * sc); r.z = f2bf(v.z * sc); r.w = f2bf(v.w * sc);
      *reinterpret_cast<ushort4*>(xb + (size_t)(c >> 3) * SL + (size_t)node * 32 + (c & 7) * 4) = r;
    }
  } else {
    const float* S; unsigned short* D; int NC;
    switch (b - featB) {
      case 0: S = W1a; D = w1aT; NC = 128; break;
      case 1: S = W1b; D = w1bT; NC = 128; break;
      case 2: S = W2a; D = w2aT; NC = 64;  break;
      case 3: S = W2b; D = w2bT; NC = 64;  break;
      case 4: S = Wf1; D = wf1T; NC = 128; break;
      default: S = Wf2; D = wf2T; NC = 128; break;
    }
    int total = 128 * NC;
    for (int i = t; i < total; i += 256) {
      int k = i / NC, n = i - k * NC;
      D[n * 128 + k] = f2bf(S[i]);
    }
  }
}

// ---- gather32s: slice-phased gather over sliced buffers ---------------------------
// grid.x = 4*nodeBlocks, slice = bid / nodeBlocks (slices dispatch in phases so each
// XCD's L2 holds the active 3.2 MB slice). One wave/node: 16 edge slots x 4 chunks.
__global__ __launch_bounds__(256)
void gather32s(const int* __restrict__ row_off, const int* __restrict__ csr_src,
               const unsigned short* __restrict__ xb,
               unsigned short* __restrict__ ob, int N, int nodeBlocks, size_t SL) {
  int bid = blockIdx.x;
  int slice = bid / nodeBlocks;
  int nb = bid - slice * nodeBlocks;
  int n = nb * 4 + (threadIdx.x >> 6);
  if (n >= N) return;
  int lane = threadIdx.x & 63;
  int ch = lane & 3, es = lane >> 2;           // 16B chunk 0..3, edge slot 0..15
  const unsigned short* base = xb + (size_t)slice * SL;
  int beg = row_off[n], end = row_off[n + 1];
  float a[8] = {0.f, 0.f, 0.f, 0.f, 0.f, 0.f, 0.f, 0.f};
  int k = beg + es;
  for (; k + 16 < end; k += 32) {              // 32 edges per wave-iter (2 per slot)
    int s0 = csr_src[k], s1 = csr_src[k + 16];
    uint4 v0 = *reinterpret_cast<const uint4*>(base + (size_t)s0 * 32 + ch * 8);
    uint4 v1 = *reinterpret_cast<const uint4*>(base + (size_t)s1 * 32 + ch * 8);
    a[0] += bflo(v0.x) + bflo(v1.x); a[1] += bfhi(v0.x) + bfhi(v1.x);
    a[2] += bflo(v0.y) + bflo(v1.y); a[3] += bfhi(v0.y) + bfhi(v1.y);
    a[4] += bflo(v0.z) + bflo(v1.z); a[5] += bfhi(v0.z) + bfhi(v1.z);
    a[6] += bflo(v0.w) + bflo(v1.w); a[7] += bfhi(v0.w) + bfhi(v1.w);
  }
  if (k < end) {
    int s0 = csr_src[k];
    uint4 v0 = *reinterpret_cast<const uint4*>(base + (size_t)s0 * 32 + ch * 8);
    a[0] += bflo(v0.x); a[1] += bfhi(v0.x);
    a[2] += bflo(v0.y); a[3] += bfhi(v0.y);
    a[4] += bflo(v0.z); a[5] += bfhi(v0.z);
    a[6] += bflo(v0.w); a[7] += bfhi(v0.w);
  }
#pragma unroll
  for (int o = 4; o < 64; o <<= 1)
#pragma unroll
    for (int i = 0; i < 8; ++i) a[i] += __shfl_xor(a[i], o, 64);
  if (lane < 4) {
    uint4 r;
    r.x = (unsigned int)f2bf(a[0]) | ((unsigned int)f2bf(a[1]) << 16);
    r.y = (unsigned int)f2bf(a[2]) | ((unsigned int)f2bf(a[3]) << 16);
    r.z = (unsigned int)f2bf(a[4]) | ((unsigned int)f2bf(a[5]) << 16);
    r.w = (unsigned int)f2bf(a[6]) | ((unsigned int)f2bf(a[7]) << 16);
    *reinterpret_cast<uint4*>(ob + (size_t)slice * SL + (size_t)n * 32 + lane * 8) = r;
  }
}

// ---- gemm_mid_lds: branch-per-block; W1^T in LDS (R15 win); sliced A/z ------------
__global__ __launch_bounds__(256)
void gemm_mid_lds(const unsigned short* __restrict__ aggb, size_t SL,
                  const unsigned short* __restrict__ w1aT, const float* __restrict__ b1a,
                  const unsigned short* __restrict__ w1bT, const float* __restrict__ b1b,
                  const unsigned short* __restrict__ w2aT,
                  const unsigned short* __restrict__ w2bT,
                  const int* __restrict__ deg_s, const int* __restrict__ deg_d,
                  unsigned short* __restrict__ zb, int N) {
  __shared__ unsigned short w1s[128 * 128];   // 32 KB, rows XOR-swizzled by (row&7)<<4
  __shared__ unsigned short h1s[64 * 128];    // 16 KB, XOR-swizzled, wave-private rows
  int br = blockIdx.y;
  const unsigned short* w1T = br ? w1bT : w1aT;
  const float* b1 = br ? b1b : b1a;
  const unsigned short* w2T = br ? w2bT : w2aT;
  int t = threadIdx.x, wid = t >> 6, lane = t & 63;
  int m0 = blockIdx.x * 64;
  int ll = lane & 15, lg = lane >> 4;
  int rA = wid * 16 + ll;
  int rw0 = m0 + wid * 16 + lg * 4;
  int rl0 = wid * 16 + lg * 4;

  // ---- A-frags from sliced aggb: A[k] lives entirely in slice k ----
  int rowA = min(m0 + rA, N - 1);
  bf16x8 A[4];
#pragma unroll
  for (int k = 0; k < 4; ++k)
    A[k] = *reinterpret_cast<const bf16x8*>(aggb + (size_t)k * SL + (size_t)rowA * 32 + lg * 8);

  float rsi[4], rso[4];
#pragma unroll
  for (int j = 0; j < 4; ++j) {
    int m = min(rw0 + j, N - 1);
    rsi[j] = degrs(deg_d[m]);
    rso[j] = degrs(deg_s[m]);
  }

  // ---- stage w1T into LDS: 2048 uint4, coalesced; swizzle byte ^= (row&7)<<4 ----
  {
    char* w1c = (char*)w1s;
#pragma unroll
    for (int it = 0; it < 8; ++it) {
      int i = t + it * 256;                 // i in [0, 2048)
      int row = i >> 4;                     // 16 uint4 per 128-ushort row
      int cb = (i & 15) << 4;               // byte offset in row
      uint4 v = *reinterpret_cast<const uint4*>(w1T + row * 128 + (cb >> 1));
      *reinterpret_cast<uint4*>(w1c + row * 256 + (cb ^ ((row & 7) << 4))) = v;
    }
  }
  __syncthreads();

  // ---- gemm1: B from LDS ----
  const char* w1c = (const char*)w1s;
#pragma unroll
  for (int c = 0; c < 8; ++c) {
    int row = c * 16 + ll;
    int swb = (row & 7) << 4;
    f32x4 acc = {0.f, 0.f, 0.f, 0.f};
#pragma unroll
    for (int k = 0; k < 4; ++k) {
      bf16x8 B = *reinterpret_cast<const bf16x8*>(w1c + row * 256 + ((lg * 16 + k * 64) ^ swb));
      acc = MFMA_B16(A[k], B, acc);
    }
    int n = c * 16 + ll;
    float bv = b1[n];
#pragma unroll
    for (int j = 0; j < 4; ++j) {
      float v = fmaxf(fmaf(acc[j], rsi[j], bv), 0.f) * rso[j];
      int r = rl0 + j;
      h1s[r * 128 + (n ^ ((r & 7) << 3))] = f2bf(v);
    }
  }
  // same-wave lockstep LDS RAW: in-order DS ops, no barrier needed

  // ---- gemm2: z half = h1s @ W2x -> zb (sliced) cols [br*64, br*64+64) ----
  bf16x8 A2[4];
#pragma unroll
  for (int k = 0; k < 4; ++k)
    A2[k] = *reinterpret_cast<const bf16x8*>(
        h1s + rA * 128 + ((lg * 8 + k * 32) ^ ((rA & 7) << 3)));
#pragma unroll
  for (int c = 0; c < 4; ++c) {
    const unsigned short* bp = w2T + (size_t)(c * 16 + ll) * 128 + lg * 8;
    f32x4 acc = {0.f, 0.f, 0.f, 0.f};
#pragma unroll
    for (int k = 0; k < 4; ++k)
      acc = MFMA_B16(A2[k], *reinterpret_cast<const bf16x8*>(bp + k * 32), acc);
    int n = br * 64 + c * 16 + ll;
    size_t zoff = (size_t)(n >> 5) * SL + (n & 31);
#pragma unroll
    for (int j = 0; j < 4; ++j) {
      int m = rw0 + j;
      if (m < N) zb[zoff + (size_t)m * 32] = f2bf(acc[j]);
    }
  }
}

// ---- fused_tail5: 256 threads / 64 rows; wf1T+wf2T staged in LDS (R16 win);
// sliced agg2z/featb loads. ffb OVERLAYS wf1s after barrier #2.
__global__ __launch_bounds__(256)
void fused_tail5(const unsigned short* __restrict__ agg2z,  // sliced [4][N][32] bf16
                 const unsigned short* __restrict__ featb,  // sliced = feat*rs_out
                 size_t SL,
                 const float* __restrict__ b2a, const float* __restrict__ b2b,
                 const int* __restrict__ deg_s, const int* __restrict__ deg_d,
                 const float* __restrict__ ln_g, const float* __restrict__ ln_b,
                 const unsigned short* __restrict__ wf1T, const float* __restrict__ bf1,
                 const unsigned short* __restrict__ wf2T, const float* __restrict__ bf2,
                 float* __restrict__ out, int N) {
  __shared__ unsigned short wf1s[128 * 128];  // 32 KB; first 16 KB reused as ffb
  __shared__ unsigned short wf2s[128 * 128];  // 32 KB
  __shared__ unsigned short hsb[64 * 128];    // 16 KB, wave-private rows
  unsigned short* ffb = wf1s;                 // overlay after barrier #2
  int t = threadIdx.x, wid = t >> 6, lane = t & 63;
  int m0 = blockIdx.x * 64;
  int ll = lane & 15, lg = lane >> 4;
  int rl0 = wid * 16 + lg * 4;                // local C-row base (this lane's 4 rows)

  // ---- stage wf1T, wf2T into LDS (coalesced uint4, row-swizzled) ----
  {
    char* d1 = (char*)wf1s;
    char* d2 = (char*)wf2s;
#pragma unroll
    for (int it = 0; it < 8; ++it) {
      int i = t + it * 256;
      int row = i >> 4;
      int cb = (i & 15) << 4;
      uint4 v1 = *reinterpret_cast<const uint4*>(wf1T + row * 128 + (cb >> 1));
      uint4 v2 = *reinterpret_cast<const uint4*>(wf2T + row * 128 + (cb >> 1));
      *reinterpret_cast<uint4*>(d1 + row * 256 + (cb ^ ((row & 7) << 4))) = v1;
      *reinterpret_cast<uint4*>(d2 + row * 256 + (cb ^ ((row & 7) << 4))) = v2;
    }
  }

  float rsv[4], sqs[4];
#pragma unroll
  for (int j = 0; j < 4; ++j) {
    int m = min(m0 + rl0 + j, N - 1);
    rsv[j] = degrs(deg_d[m]);
    sqs[j] = sqrtf((float)max(deg_s[m], 1));   // undoes featb's rs_out pre-scale
  }

  // ---- phase 1: cat = rs_in * agg2z + [b2a|b2b] (overlaps staging latency) ----
  float x[8][4];
  float s[4] = {0.f, 0.f, 0.f, 0.f}, q[4] = {0.f, 0.f, 0.f, 0.f};
#pragma unroll
  for (int ct = 0; ct < 8; ++ct) {
    int n = ct * 16 + ll;
    size_t noff = (size_t)(n >> 5) * SL + (n & 31);
    float bv = (n < 64) ? b2a[n] : b2b[n - 64];
#pragma unroll
    for (int j = 0; j < 4; ++j) {
      int m = min(m0 + rl0 + j, N - 1);
      float v = fmaf(bfs(agg2z[noff + (size_t)m * 32]), rsv[j], bv);
      x[ct][j] = v;
      s[j] += v;
      q[j] += v * v;
    }
  }

  // ---- phase 2: in-register LN + features residual -> hsb (wave-private) ----
#pragma unroll
  for (int o = 1; o < 16; o <<= 1) {
#pragma unroll
    for (int j = 0; j < 4; ++j) {
      s[j] += __shfl_xor(s[j], o, 64);
      q[j] += __shfl_xor(q[j], o, 64);
    }
  }
  float mu[4], rstd[4];
#pragma unroll
  for (int j = 0; j < 4; ++j) {
    mu[j] = s[j] * (1.f / 128.f);
    float var = fmaxf(q[j] * (1.f / 128.f) - mu[j] * mu[j], 0.f);
    rstd[j] = rsqrtf(var + LN_EPS);
  }
#pragma unroll
  for (int ct = 0; ct < 8; ++ct) {
    int n = ct * 16 + ll;
    size_t noff = (size_t)(n >> 5) * SL + (n & 31);
    float gv = ln_g[n], bv = ln_b[n];
#pragma unroll
    for (int j = 0; j < 4; ++j) {
      int m = min(m0 + rl0 + j, N - 1);
      float fv = bfs(featb[noff + (size_t)m * 32]) * sqs[j];   // ~= feat[m][n]
      float hv = fv + (x[ct][j] - mu[j]) * rstd[j] * gv + bv;
      x[ct][j] = hv;                                     // keep f32 h for residual
      int r = rl0 + j;
      hsb[r * 128 + (n ^ ((r & 7) << 3))] = f2bf(hv);    // swizzled bf16 for FFN1
    }
  }
  __syncthreads();   // barrier #1: staged weights visible to all waves

  // ---- phase 3: FFN1 = relu(hs @ Wf1 + bf1), results in registers ----
  float xf[8][4];
  {
    int rloc = wid * 16 + ll;
    int swr = (rloc & 7) << 3;
    bf16x8 A[4];
#pragma unroll
    for (int k = 0; k < 4; ++k)
      A[k] = *reinterpret_cast<const bf16x8*>(hsb + rloc * 128 + ((lg * 8 + k * 32) ^ swr));
    const char* w1c = (const char*)wf1s;
#pragma unroll
    for (int c = 0; c < 8; ++c) {
      int row = c * 16 + ll;
      int swb = (row & 7) << 4;
      f32x4 a = {0.f, 0.f, 0.f, 0.f};
#pragma unroll
      for (int k = 0; k < 4; ++k) {
        bf16x8 B = *reinterpret_cast<const bf16x8*>(w1c + row * 256 + ((lg * 16 + k * 64) ^ swb));
        a = MFMA_B16(A[k], B, a);
      }
      float bv = bf1[c * 16 + ll];
#pragma unroll
      for (int j = 0; j < 4; ++j) xf[c][j] = fmaxf(a[j] + bv, 0.f);
    }
  }
  __syncthreads();   // barrier #2: all waves done reading wf1s -> ffb overlay safe

  // ---- write ffb (overlay), wave-private rows ----
#pragma unroll
  for (int c = 0; c < 8; ++c) {
    int n = c * 16 + ll;
#pragma unroll
    for (int j = 0; j < 4; ++j) {
      int r = rl0 + j;
      ffb[r * 128 + (n ^ ((r & 7) << 3))] = f2bf(xf[c][j]);
    }
  }

  // ---- phase 4: FFN2 + residual -> out (B from wf2s) ----
  {
    int rloc = wid * 16 + ll;
    int swr = (rloc & 7) << 3;
    bf16x8 A[4];
#pragma unroll
    for (int k = 0; k < 4; ++k)
      A[k] = *reinterpret_cast<const bf16x8*>(ffb + rloc * 128 + ((lg * 8 + k * 32) ^ swr));
    const char* w2c = (const char*)wf2s;
#pragma unroll
    for (int c = 0; c < 8; ++c) {
      int row = c * 16 + ll;
      int swb = (row & 7) << 4;
      f32x4 a = {0.f, 0.f, 0.f, 0.f};
#pragma unroll
      for (int k = 0; k < 4; ++k) {
        bf16x8 B = *reinterpret_cast<const bf16x8*>(w2c + row * 256 + ((lg * 16 + k * 64) ^ swb));
        a = MFMA_B16(A[k], B, a);
      }
      int n = c * 16 + ll;
      float bv = bf2[n];
#pragma unroll
      for (int j = 0; j < 4; ++j) {
        int m = m0 + rl0 + j;
        if (m < N) out[(size_t)m * 128 + n] = x[c][j] + a[j] + bv;
      }
    }
  }
}

extern "C" void kernel_launch(void* const* d_in, const int* in_sizes, int n_in,
                              void* d_out, int out_size, void* d_ws, size_t ws_size,
                              hipStream_t stream) {
  const float* features = (const float*)d_in[0];
  const int*   src      = (const int*)d_in[1];
  const int*   dst      = (const int*)d_in[2];
  const float* W1a = (const float*)d_in[3];  const float* b1a = (const float*)d_in[4];
  const float* W2a = (const float*)d_in[5];  const float* b2a = (const float*)d_in[6];
  const float* W1b = (const float*)d_in[7];  const float* b1b = (const float*)d_in[8];
  const float* W2b = (const float*)d_in[9];  const float* b2b = (const float*)d_in[10];
  const float* Wf1 = (const float*)d_in[11]; const float* bf1 = (const float*)d_in[12];
  const float* Wf2 = (const float*)d_in[13]; const float* bf2 = (const float*)d_in[14];
  const float* ln_g = (const float*)d_in[15];
  const float* ln_b = (const float*)d_in[16];

  const int N = in_sizes[0] / 128;
  const int E = in_sizes[1];
  float* out = (float*)d_out;

  const int nbk = (N + 127) >> BSH;          // buckets of 128 nodes
  const int L = 2 * nbk * NBLK;              // concatenated blk_cnt length
  const size_t SL = (size_t)N * 32;          // slice stride (elements)

  size_t off_b = 0;
  char* wsb = (char*)d_ws;
  auto take = [&](size_t bytes) -> void* {
    void* p = wsb + off_b;
    off_b += (bytes + 255) & ~(size_t)255;
    return p;
  };
  int* blk_cnt = (int*)take((size_t)L * 4);
  int* boff    = (int*)take((size_t)L * 4);
  int* part    = (int*)take((size_t)1024 * 4);
  unsigned int* pairs = (unsigned int*)take((size_t)2 * E * 4);
  int* deg_s   = (int*)take((size_t)N * 4);
  int* deg_d   = (int*)take((size_t)N * 4);
  int* row_off = (int*)take((size_t)(N + 1) * 4);
  int* csr_src = (int*)take((size_t)E * 4);
  unsigned short* featb = (unsigned short*)take((size_t)N * 128 * 2);
  unsigned short* aggb  = (unsigned short*)take((size_t)N * 128 * 2);
  unsigned short* zb    = (unsigned short*)take((size_t)N * 128 * 2);
  unsigned short* agg2z = (unsigned short*)take((size_t)N * 128 * 2);
  unsigned short* w1aT  = (unsigned short*)take(128 * 128 * 2);
  unsigned short* w1bT  = (unsigned short*)take(128 * 128 * 2);
  unsigned short* w2aT  = (unsigned short*)take(64 * 128 * 2);
  unsigned short* w2bT  = (unsigned short*)take(64 * 128 * 2);
  unsigned short* wf1T  = (unsigned short*)take(128 * 128 * 2);
  unsigned short* wf2T  = (unsigned short*)take(128 * 128 * 2);

  const int nodeBlocks = (N + 3) / 4;
  const int mtiles = (N + 63) / 64;
  const int n4 = (N * 128) / 4;
  const int featB = (n4 + 255) / 256;
  const int scanL = (L + 1023) / 1024;

  // A) per-block bucket histograms (no global atomics, no memsets)
  bucket_hist<<<NBLK, 256, 0, stream>>>(src, dst, blk_cnt, E, nbk);
  // B) exclusive scan of concatenated counts -> absolute write offsets
  scan_partial_g<<<scanL, 256, 0, stream>>>(blk_cnt, part, L);
  scan_final_g<<<scanL, 256, 0, stream>>>(blk_cnt, part, boff, L);
  // C) bucket-partition edges (LDS cursors only)
  bucket_scatter<<<NBLK, 256, 0, stream>>>(src, dst, boff, pairs, E, nbk);
  // D) degrees + row_off + CSR fill (self-contained per block -> no cross-block race)
  bucket_finish<<<2 * nbk, 256, 0, stream>>>(
      pairs, boff, row_off, deg_d, deg_s, csr_src, N, E, nbk);
  // E) converts (featb sliced; reads deg_s produced by D)
  convert_all<<<featB + 6, 256, 0, stream>>>(
      features, deg_s, featb, n4, SL,
      W1a, W1b, W2a, W2b, Wf1, Wf2,
      w1aT, w1bT, w2aT, w2bT, wf1T, wf2T);
  // first aggregation (slice-phased)
  gather32s<<<4 * nodeBlocks, 256, 0, stream>>>(row_off, csr_src, featb, aggb,
                                                N, nodeBlocks, SL);
  // z = [h1a@W2a | h1b@W2b]  (branch-parallel, W1^T staged in LDS)
  gemm_mid_lds<<<dim3(mtiles, 2), 256, 0, stream>>>(aggb, SL, w1aT, b1a, w1bT, b1b,
                                                    w2aT, w2bT, deg_s, deg_d, zb, N);
  // second aggregation over z (slice-phased)
  gather32s<<<4 * nodeBlocks, 256, 0, stream>>>(row_off, csr_src, zb, agg2z,
                                                N, nodeBlocks, SL);
  // tail: scale+bias -> LN+resid -> FFN1 -> FFN2 -> out (FFN weights in LDS)
  fused_tail5<<<mtiles, 256, 0, stream>>>(agg2z, featb, SL, b2a, b2b,
                                          deg_s, deg_d, ln_g, ln_b,
                                          wf1T, bf1, wf2T, bf2, out, N);
}

// Round 18
// 179.698 us; speedup vs baseline: 1.4293x; 1.4293x over previous
//
#include <hip/hip_runtime.h>

#define LN_EPS 1e-5f
#define NBLK 512            // blocks for bucket hist/scatter passes
#define BSH  7              // 128 nodes per bucket
#define MAXB 512            // max buckets (N <= 65536)

typedef __attribute__((ext_vector_type(8))) short bf16x8;   // 8 bf16 = 4 VGPR (MFMA A/B frag)
typedef __attribute__((ext_vector_type(4))) float f32x4;    // MFMA C/D frag

#define MFMA_B16(a, b, c) __builtin_amdgcn_mfma_f32_16x16x32_bf16((a), (b), (c), 0, 0, 0)

__device__ __forceinline__ float bflo(unsigned int u) {
  return __builtin_bit_cast(float, u << 16);
}
__device__ __forceinline__ float bfhi(unsigned int u) {
  return __builtin_bit_cast(float, u & 0xffff0000u);
}
__device__ __forceinline__ float bfs(unsigned short u) {    // single bf16 -> f32
  return __builtin_bit_cast(float, (unsigned int)u << 16);
}
__device__ __forceinline__ unsigned short f2bf(float f) {   // f32 -> bf16 RNE
  unsigned int u = __builtin_bit_cast(unsigned int, f);
  u += 0x7fffu + ((u >> 16) & 1u);
  return (unsigned short)(u >> 16);
}
__device__ __forceinline__ float degrs(int d) { return rsqrtf((float)max(d, 1)); }

// ---- A: per-block bucket histograms (dst and src), no global atomics -------------
__global__ __launch_bounds__(256)
void bucket_hist(const int* __restrict__ src, const int* __restrict__ dst,
                 int* __restrict__ blk_cnt, int E, int nbk) {
  __shared__ int h[2 * MAXB];
  int b = blockIdx.x, t = threadIdx.x;
  for (int i = t; i < nbk; i += 256) { h[i] = 0; h[MAXB + i] = 0; }
  __syncthreads();
  int chunk = (E + NBLK - 1) / NBLK;
  int beg = b * chunk, end = min(E, beg + chunk);
  for (int i = beg + t; i < end; i += 256) {
    atomicAdd(&h[dst[i] >> BSH], 1);
    atomicAdd(&h[MAXB + (src[i] >> BSH)], 1);
  }
  __syncthreads();
  for (int i = t; i < nbk; i += 256) {
    blk_cnt[(size_t)i * NBLK + b] = h[i];
    blk_cnt[(size_t)(nbk + i) * NBLK + b] = h[MAXB + i];
  }
}

// ---- generic hierarchical exclusive scan (partial + final), for boff --------------
__global__ __launch_bounds__(256)
void scan_partial_g(const int* __restrict__ v, int* __restrict__ part, int L) {
  __shared__ int sd[256];
  int base = blockIdx.x * 1024;
  int t = threadIdx.x;
  int s = 0;
#pragma unroll
  for (int i = 0; i < 4; ++i) { int idx = base + t * 4 + i; if (idx < L) s += v[idx]; }
  sd[t] = s; __syncthreads();
  for (int o = 128; o > 0; o >>= 1) { if (t < o) sd[t] += sd[t + o]; __syncthreads(); }
  if (t == 0) part[blockIdx.x] = sd[0];
}

__global__ __launch_bounds__(256)
void scan_final_g(const int* __restrict__ v, const int* __restrict__ part,
                  int* __restrict__ off, int L) {
  __shared__ int sd[256];
  __shared__ int pex_s;
  int base = blockIdx.x * 1024;
  int t = threadIdx.x;
  if (t < 64) {
    int p = 0;
    for (int i = t; i < (int)blockIdx.x; i += 64) p += part[i];
#pragma unroll
    for (int o = 1; o < 64; o <<= 1) p += __shfl_xor(p, o, 64);
    if (t == 0) pex_s = p;
  }
  int loc[4]; int s = 0;
#pragma unroll
  for (int i = 0; i < 4; ++i) {
    int idx = base + t * 4 + i;
    loc[i] = (idx < L) ? v[idx] : 0;
    s += loc[i];
  }
  sd[t] = s; __syncthreads();
  for (int o = 1; o < 256; o <<= 1) {
    int x = (t >= o) ? sd[t - o] : 0;
    __syncthreads();
    sd[t] += x;
    __syncthreads();
  }
  int excl = sd[t] - s + pex_s;
#pragma unroll
  for (int i = 0; i < 4; ++i) {
    int idx = base + t * 4 + i;
    if (idx < L) off[idx] = excl;
    excl += loc[i];
  }
}

// ---- C: bucket-partition edges; LDS cursors; writes bucket-contiguous regions -----
__global__ __launch_bounds__(256)
void bucket_scatter(const int* __restrict__ src, const int* __restrict__ dst,
                    const int* __restrict__ off, unsigned int* __restrict__ pairs,
                    int E, int nbk) {
  __shared__ int cur[2 * MAXB];
  int b = blockIdx.x, t = threadIdx.x;
  for (int i = t; i < nbk; i += 256) {
    cur[i] = off[(size_t)i * NBLK + b];
    cur[MAXB + i] = off[(size_t)(nbk + i) * NBLK + b];
  }
  __syncthreads();
  int chunk = (E + NBLK - 1) / NBLK;
  int beg = b * chunk, end = min(E, beg + chunk);
  for (int i = beg + t; i < end; i += 256) {
    int d = dst[i], s = src[i];
    int p1 = atomicAdd(&cur[d >> BSH], 1);
    pairs[p1] = ((unsigned int)s << BSH) | (unsigned int)(d & 127);
    int p2 = atomicAdd(&cur[MAXB + (s >> BSH)], 1);
    pairs[p2] = (unsigned int)(s & 127);
  }
}

// ---- bucket_finish: dst buckets do hist+scan+row_off+deg_d AND csr fill; src
// buckets write deg_s. NO converts here (R13's cross-block race lesson).
__global__ __launch_bounds__(256)
void bucket_finish(const unsigned int* __restrict__ pairs, const int* __restrict__ off,
                   int* __restrict__ row_off, int* __restrict__ deg_d,
                   int* __restrict__ deg_s, int* __restrict__ csr_src,
                   int N, int E, int nbk) {
  __shared__ int h[128];
  __shared__ int cur[128];
  int g = blockIdx.x, t = threadIdx.x;
  if (t < 128) h[t] = 0;
  __syncthreads();
  if (g < nbk) {
    int base = off[(size_t)g * NBLK];
    int end  = off[(size_t)(g + 1) * NBLK];     // g==nbk-1 -> start of src region == E
    for (int i = base + t; i < end; i += 256) atomicAdd(&h[pairs[i] & 127], 1);
    __syncthreads();
    int orig = (t < 128) ? h[t] : 0;
    for (int o = 1; o < 128; o <<= 1) {          // Hillis-Steele inclusive scan
      int v = (t < 128 && t >= o) ? h[t - o] : 0;
      __syncthreads();
      if (t < 128) h[t] += v;
      __syncthreads();
    }
    if (t < 128) {
      int excl = base + h[t] - orig;
      cur[t] = excl;
      int node = (g << BSH) + t;
      if (node < N) { row_off[node] = excl; deg_d[node] = orig; }
    }
    if (g == nbk - 1 && t == 0) row_off[N] = E;
    __syncthreads();
    for (int i = base + t; i < end; i += 256) {
      unsigned int v = pairs[i];
      int pos = atomicAdd(&cur[v & 127], 1);
      csr_src[pos] = (int)(v >> BSH);
    }
  } else {
    int j = g - nbk;
    int beg = off[(size_t)(nbk + j) * NBLK];
    int end = (j + 1 < nbk) ? off[(size_t)(nbk + j + 1) * NBLK] : 2 * E;
    for (int i = beg + t; i < end; i += 256) atomicAdd(&h[pairs[i] & 127], 1);
    __syncthreads();
    int nb0 = j << BSH;
    if (t < 128 && nb0 + t < N) deg_s[nb0 + t] = h[t];
  }
}

// ---- convert_all: featb = bf16(x*rs_out) + 6 weight transposes (after deg_s ready)
__global__ __launch_bounds__(256)
void convert_all(const float* __restrict__ x, const int* __restrict__ deg_s,
                 unsigned short* __restrict__ xb, int n4,
                 const float* __restrict__ W1a, const float* __restrict__ W1b,
                 const float* __restrict__ W2a, const float* __restrict__ W2b,
                 const float* __restrict__ Wf1, const float* __restrict__ Wf2,
                 unsigned short* __restrict__ w1aT, unsigned short* __restrict__ w1bT,
                 unsigned short* __restrict__ w2aT, unsigned short* __restrict__ w2bT,
                 unsigned short* __restrict__ wf1T, unsigned short* __restrict__ wf2T) {
  const int featB = (n4 + 255) >> 8;
  int b = blockIdx.x, t = threadIdx.x;
  if (b < featB) {
    int i = b * 256 + t;
    if (i < n4) {
      float sc = degrs(deg_s[i >> 5]);          // 32 float4 per 128-wide row
      float4 v = reinterpret_cast<const float4*>(x)[i];
      ushort4 r;
      r.x = f2bf(v.x * sc); r.y = f2bf(v.y * sc); r.z = f2bf(v.z * sc); r.w = f2bf(v.w * sc);
      reinterpret_cast<ushort4*>(xb)[i] = r;
    }
  } else {
    const float* S; unsigned short* D; int NC;
    switch (b - featB) {
      case 0: S = W1a; D = w1aT; NC = 128; break;
      case 1: S = W1b; D = w1bT; NC = 128; break;
      case 2: S = W2a; D = w2aT; NC = 64;  break;
      case 3: S = W2b; D = w2bT; NC = 64;  break;
      case 4: S = Wf1; D = wf1T; NC = 128; break;
      default: S = Wf2; D = wf2T; NC = 128; break;
    }
    int total = 128 * NC;
    for (int i = t; i < total; i += 256) {
      int k = i / NC, n = i - k * NC;
      D[n * 128 + k] = f2bf(S[i]);
    }
  }
}

// ---------------- gather 128-wide: one wave/node, uint4 chunks, 4 edge slots -------
// Validated optimum shape (R17's 16-slot sliced variant regressed 2.5x: index
// traffic x4 + shuffle overhead). Dedicated high-occupancy kernel, no LDS.
__global__ __launch_bounds__(256)
void gather128b(const int* __restrict__ row_off, const int* __restrict__ csr_src,
                const unsigned short* __restrict__ xb,
                unsigned short* __restrict__ ob, int N) {
  int n = blockIdx.x * 4 + (threadIdx.x >> 6);
  if (n >= N) return;
  int lane = threadIdx.x & 63;
  int ch = lane & 15, es = lane >> 4;        // 16B chunk, edge slot 0..3
  int beg = row_off[n], end = row_off[n + 1];
  float a[8] = {0.f, 0.f, 0.f, 0.f, 0.f, 0.f, 0.f, 0.f};
  int k = beg + es;
  for (; k + 4 < end; k += 8) {              // 8 edges per wave-iter (2 per slot)
    int s0 = csr_src[k], s1 = csr_src[k + 4];
    uint4 v0 = *reinterpret_cast<const uint4*>(xb + (size_t)s0 * 128 + ch * 8);
    uint4 v1 = *reinterpret_cast<const uint4*>(xb + (size_t)s1 * 128 + ch * 8);
    a[0] += bflo(v0.x) + bflo(v1.x); a[1] += bfhi(v0.x) + bfhi(v1.x);
    a[2] += bflo(v0.y) + bflo(v1.y); a[3] += bfhi(v0.y) + bfhi(v1.y);
    a[4] += bflo(v0.z) + bflo(v1.z); a[5] += bfhi(v0.z) + bfhi(v1.z);
    a[6] += bflo(v0.w) + bflo(v1.w); a[7] += bfhi(v0.w) + bfhi(v1.w);
  }
  if (k < end) {
    int s0 = csr_src[k];
    uint4 v0 = *reinterpret_cast<const uint4*>(xb + (size_t)s0 * 128 + ch * 8);
    a[0] += bflo(v0.x); a[1] += bfhi(v0.x);
    a[2] += bflo(v0.y); a[3] += bfhi(v0.y);
    a[4] += bflo(v0.z); a[5] += bfhi(v0.z);
    a[6] += bflo(v0.w); a[7] += bfhi(v0.w);
  }
#pragma unroll
  for (int o = 16; o < 64; o <<= 1)
#pragma unroll
    for (int i = 0; i < 8; ++i) a[i] += __shfl_xor(a[i], o, 64);
  if (es == 0) {
    uint4 r;
    r.x = (unsigned int)f2bf(a[0]) | ((unsigned int)f2bf(a[1]) << 16);
    r.y = (unsigned int)f2bf(a[2]) | ((unsigned int)f2bf(a[3]) << 16);
    r.z = (unsigned int)f2bf(a[4]) | ((unsigned int)f2bf(a[5]) << 16);
    r.w = (unsigned int)f2bf(a[6]) | ((unsigned int)f2bf(a[7]) << 16);
    *reinterpret_cast<uint4*>(ob + (size_t)n * 128 + ch * 8) = r;
  }
}

// ---- gemm_mid_lds: branch-per-block; W1^T staged in LDS (R15 win) -----------------
__global__ __launch_bounds__(256)
void gemm_mid_lds(const unsigned short* __restrict__ aggb,
                  const unsigned short* __restrict__ w1aT, const float* __restrict__ b1a,
                  const unsigned short* __restrict__ w1bT, const float* __restrict__ b1b,
                  const unsigned short* __restrict__ w2aT,
                  const unsigned short* __restrict__ w2bT,
                  const int* __restrict__ deg_s, const int* __restrict__ deg_d,
                  unsigned short* __restrict__ zb, int N) {
  __shared__ unsigned short w1s[128 * 128];   // 32 KB, rows XOR-swizzled by (row&7)<<4
  __shared__ unsigned short h1s[64 * 128];    // 16 KB, XOR-swizzled, wave-private rows
  int br = blockIdx.y;
  const unsigned short* w1T = br ? w1bT : w1aT;
  const float* b1 = br ? b1b : b1a;
  const unsigned short* w2T = br ? w2bT : w2aT;
  int t = threadIdx.x, wid = t >> 6, lane = t & 63;
  int m0 = blockIdx.x * 64;
  int ll = lane & 15, lg = lane >> 4;
  int rA = wid * 16 + ll;
  int rw0 = m0 + wid * 16 + lg * 4;
  int rl0 = wid * 16 + lg * 4;

  // ---- A-frags from global first (overlaps the staging loads) ----
  const unsigned short* ap = aggb + (size_t)min(m0 + rA, N - 1) * 128 + lg * 8;
  bf16x8 A[4];
#pragma unroll
  for (int k = 0; k < 4; ++k) A[k] = *reinterpret_cast<const bf16x8*>(ap + k * 32);

  float rsi[4], rso[4];
#pragma unroll
  for (int j = 0; j < 4; ++j) {
    int m = min(rw0 + j, N - 1);
    rsi[j] = degrs(deg_d[m]);
    rso[j] = degrs(deg_s[m]);
  }

  // ---- stage w1T into LDS: 2048 uint4, coalesced; swizzle byte ^= (row&7)<<4 ----
  {
    char* w1c = (char*)w1s;
#pragma unroll
    for (int it = 0; it < 8; ++it) {
      int i = t + it * 256;                 // i in [0, 2048)
      int row = i >> 4;                     // 16 uint4 per 128-ushort row
      int cb = (i & 15) << 4;               // byte offset in row
      uint4 v = *reinterpret_cast<const uint4*>(w1T + row * 128 + (cb >> 1));
      *reinterpret_cast<uint4*>(w1c + row * 256 + (cb ^ ((row & 7) << 4))) = v;
    }
  }
  __syncthreads();

  // ---- gemm1: B from LDS ----
  const char* w1c = (const char*)w1s;
#pragma unroll
  for (int c = 0; c < 8; ++c) {
    int row = c * 16 + ll;
    int swb = (row & 7) << 4;
    f32x4 acc = {0.f, 0.f, 0.f, 0.f};
#pragma unroll
    for (int k = 0; k < 4; ++k) {
      bf16x8 B = *reinterpret_cast<const bf16x8*>(w1c + row * 256 + ((lg * 16 + k * 64) ^ swb));
      acc = MFMA_B16(A[k], B, acc);
    }
    int n = c * 16 + ll;
    float bv = b1[n];
#pragma unroll
    for (int j = 0; j < 4; ++j) {
      float v = fmaxf(fmaf(acc[j], rsi[j], bv), 0.f) * rso[j];
      int r = rl0 + j;
      h1s[r * 128 + (n ^ ((r & 7) << 3))] = f2bf(v);
    }
  }
  // same-wave lockstep LDS RAW: in-order DS ops, no barrier needed

  // ---- gemm2: z half = h1s @ W2x -> zb[:, br*64 : br*64+64) ----
  bf16x8 A2[4];
#pragma unroll
  for (int k = 0; k < 4; ++k)
    A2[k] = *reinterpret_cast<const bf16x8*>(
        h1s + rA * 128 + ((lg * 8 + k * 32) ^ ((rA & 7) << 3)));
#pragma unroll
  for (int c = 0; c < 4; ++c) {
    const unsigned short* bp = w2T + (size_t)(c * 16 + ll) * 128 + lg * 8;
    f32x4 acc = {0.f, 0.f, 0.f, 0.f};
#pragma unroll
    for (int k = 0; k < 4; ++k)
      acc = MFMA_B16(A2[k], *reinterpret_cast<const bf16x8*>(bp + k * 32), acc);
    int n = br * 64 + c * 16 + ll;
#pragma unroll
    for (int j = 0; j < 4; ++j) {
      int m = rw0 + j;
      if (m < N) zb[(size_t)m * 128 + n] = f2bf(acc[j]);
    }
  }
}

// ---- fused_tail5: 256 threads / 64 rows; wf1T+wf2T staged in LDS (R16 win);
// ffb OVERLAYS wf1s after barrier #2. LDS 80 KB -> 2 blocks/CU.
__global__ __launch_bounds__(256)
void fused_tail5(const unsigned short* __restrict__ agg2z,  // [N,128] bf16
                 const unsigned short* __restrict__ featb,  // [N,128] bf16 = feat*rs_out
                 const float* __restrict__ b2a, const float* __restrict__ b2b,
                 const int* __restrict__ deg_s, const int* __restrict__ deg_d,
                 const float* __restrict__ ln_g, const float* __restrict__ ln_b,
                 const unsigned short* __restrict__ wf1T, const float* __restrict__ bf1,
                 const unsigned short* __restrict__ wf2T, const float* __restrict__ bf2,
                 float* __restrict__ out, int N) {
  __shared__ unsigned short wf1s[128 * 128];  // 32 KB; first 16 KB reused as ffb
  __shared__ unsigned short wf2s[128 * 128];  // 32 KB
  __shared__ unsigned short hsb[64 * 128];    // 16 KB, wave-private rows
  unsigned short* ffb = wf1s;                 // overlay after barrier #2
  int t = threadIdx.x, wid = t >> 6, lane = t & 63;
  int m0 = blockIdx.x * 64;
  int ll = lane & 15, lg = lane >> 4;
  int rl0 = wid * 16 + lg * 4;                // local C-row base (this lane's 4 rows)

  // ---- stage wf1T, wf2T into LDS (coalesced uint4, row-swizzled) ----
  {
    char* d1 = (char*)wf1s;
    char* d2 = (char*)wf2s;
#pragma unroll
    for (int it = 0; it < 8; ++it) {
      int i = t + it * 256;
      int row = i >> 4;
      int cb = (i & 15) << 4;
      uint4 v1 = *reinterpret_cast<const uint4*>(wf1T + row * 128 + (cb >> 1));
      uint4 v2 = *reinterpret_cast<const uint4*>(wf2T + row * 128 + (cb >> 1));
      *reinterpret_cast<uint4*>(d1 + row * 256 + (cb ^ ((row & 7) << 4))) = v1;
      *reinterpret_cast<uint4*>(d2 + row * 256 + (cb ^ ((row & 7) << 4))) = v2;
    }
  }

  float rsv[4], sqs[4];
#pragma unroll
  for (int j = 0; j < 4; ++j) {
    int m = min(m0 + rl0 + j, N - 1);
    rsv[j] = degrs(deg_d[m]);
    sqs[j] = sqrtf((float)max(deg_s[m], 1));   // undoes featb's rs_out pre-scale
  }

  // ---- phase 1: cat = rs_in * agg2z + [b2a|b2b] (overlaps staging latency) ----
  float x[8][4];
  float s[4] = {0.f, 0.f, 0.f, 0.f}, q[4] = {0.f, 0.f, 0.f, 0.f};
#pragma unroll
  for (int ct = 0; ct < 8; ++ct) {
    int n = ct * 16 + ll;
    float bv = (n < 64) ? b2a[n] : b2b[n - 64];
#pragma unroll
    for (int j = 0; j < 4; ++j) {
      int m = min(m0 + rl0 + j, N - 1);
      float v = fmaf(bfs(agg2z[(size_t)m * 128 + n]), rsv[j], bv);
      x[ct][j] = v;
      s[j] += v;
      q[j] += v * v;
    }
  }

  // ---- phase 2: in-register LN + features residual -> hsb (wave-private) ----
#pragma unroll
  for (int o = 1; o < 16; o <<= 1) {
#pragma unroll
    for (int j = 0; j < 4; ++j) {
      s[j] += __shfl_xor(s[j], o, 64);
      q[j] += __shfl_xor(q[j], o, 64);
    }
  }
  float mu[4], rstd[4];
#pragma unroll
  for (int j = 0; j < 4; ++j) {
    mu[j] = s[j] * (1.f / 128.f);
    float var = fmaxf(q[j] * (1.f / 128.f) - mu[j] * mu[j], 0.f);
    rstd[j] = rsqrtf(var + LN_EPS);
  }
#pragma unroll
  for (int ct = 0; ct < 8; ++ct) {
    int n = ct * 16 + ll;
    float gv = ln_g[n], bv = ln_b[n];
#pragma unroll
    for (int j = 0; j < 4; ++j) {
      int m = min(m0 + rl0 + j, N - 1);
      float fv = bfs(featb[(size_t)m * 128 + n]) * sqs[j];   // ~= feat[m][n]
      float hv = fv + (x[ct][j] - mu[j]) * rstd[j] * gv + bv;
      x[ct][j] = hv;                                     // keep f32 h for residual
      int r = rl0 + j;
      hsb[r * 128 + (n ^ ((r & 7) << 3))] = f2bf(hv);    // swizzled bf16 for FFN1
    }
  }
  __syncthreads();   // barrier #1: staged weights visible to all waves

  // ---- phase 3: FFN1 = relu(hs @ Wf1 + bf1), results in registers ----
  float xf[8][4];
  {
    int rloc = wid * 16 + ll;
    int swr = (rloc & 7) << 3;
    bf16x8 A[4];
#pragma unroll
    for (int k = 0; k < 4; ++k)
      A[k] = *reinterpret_cast<const bf16x8*>(hsb + rloc * 128 + ((lg * 8 + k * 32) ^ swr));
    const char* w1c = (const char*)wf1s;
#pragma unroll
    for (int c = 0; c < 8; ++c) {
      int row = c * 16 + ll;
      int swb = (row & 7) << 4;
      f32x4 a = {0.f, 0.f, 0.f, 0.f};
#pragma unroll
      for (int k = 0; k < 4; ++k) {
        bf16x8 B = *reinterpret_cast<const bf16x8*>(w1c + row * 256 + ((lg * 16 + k * 64) ^ swb));
        a = MFMA_B16(A[k], B, a);
      }
      float bv = bf1[c * 16 + ll];
#pragma unroll
      for (int j = 0; j < 4; ++j) xf[c][j] = fmaxf(a[j] + bv, 0.f);
    }
  }
  __syncthreads();   // barrier #2: all waves done reading wf1s -> ffb overlay safe

  // ---- write ffb (overlay), wave-private rows ----
#pragma unroll
  for (int c = 0; c < 8; ++c) {
    int n = c * 16 + ll;
#pragma unroll
    for (int j = 0; j < 4; ++j) {
      int r = rl0 + j;
      ffb[r * 128 + (n ^ ((r & 7) << 3))] = f2bf(xf[c][j]);
    }
  }

  // ---- phase 4: FFN2 + residual -> out (B from wf2s) ----
  {
    int rloc = wid * 16 + ll;
    int swr = (rloc & 7) << 3;
    bf16x8 A[4];
#pragma unroll
    for (int k = 0; k < 4; ++k)
      A[k] = *reinterpret_cast<const bf16x8*>(ffb + rloc * 128 + ((lg * 8 + k * 32) ^ swr));
    const char* w2c = (const char*)wf2s;
#pragma unroll
    for (int c = 0; c < 8; ++c) {
      int row = c * 16 + ll;
      int swb = (row & 7) << 4;
      f32x4 a = {0.f, 0.f, 0.f, 0.f};
#pragma unroll
      for (int k = 0; k < 4; ++k) {
        bf16x8 B = *reinterpret_cast<const bf16x8*>(w2c + row * 256 + ((lg * 16 + k * 64) ^ swb));
        a = MFMA_B16(A[k], B, a);
      }
      int n = c * 16 + ll;
      float bv = bf2[n];
#pragma unroll
      for (int j = 0; j < 4; ++j) {
        int m = m0 + rl0 + j;
        if (m < N) out[(size_t)m * 128 + n] = x[c][j] + a[j] + bv;
      }
    }
  }
}

extern "C" void kernel_launch(void* const* d_in, const int* in_sizes, int n_in,
                              void* d_out, int out_size, void* d_ws, size_t ws_size,
                              hipStream_t stream) {
  const float* features = (const float*)d_in[0];
  const int*   src      = (const int*)d_in[1];
  const int*   dst      = (const int*)d_in[2];
  const float* W1a = (const float*)d_in[3];  const float* b1a = (const float*)d_in[4];
  const float* W2a = (const float*)d_in[5];  const float* b2a = (const float*)d_in[6];
  const float* W1b = (const float*)d_in[7];  const float* b1b = (const float*)d_in[8];
  const float* W2b = (const float*)d_in[9];  const float* b2b = (const float*)d_in[10];
  const float* Wf1 = (const float*)d_in[11]; const float* bf1 = (const float*)d_in[12];
  const float* Wf2 = (const float*)d_in[13]; const float* bf2 = (const float*)d_in[14];
  const float* ln_g = (const float*)d_in[15];
  const float* ln_b = (const float*)d_in[16];

  const int N = in_sizes[0] / 128;
  const int E = in_sizes[1];
  float* out = (float*)d_out;

  const int nbk = (N + 127) >> BSH;          // buckets of 128 nodes
  const int L = 2 * nbk * NBLK;              // concatenated blk_cnt length

  size_t off_b = 0;
  char* wsb = (char*)d_ws;
  auto take = [&](size_t bytes) -> void* {
    void* p = wsb + off_b;
    off_b += (bytes + 255) & ~(size_t)255;
    return p;
  };
  int* blk_cnt = (int*)take((size_t)L * 4);
  int* boff    = (int*)take((size_t)L * 4);
  int* part    = (int*)take((size_t)1024 * 4);
  unsigned int* pairs = (unsigned int*)take((size_t)2 * E * 4);
  int* deg_s   = (int*)take((size_t)N * 4);
  int* deg_d   = (int*)take((size_t)N * 4);
  int* row_off = (int*)take((size_t)(N + 1) * 4);
  int* csr_src = (int*)take((size_t)E * 4);
  unsigned short* featb = (unsigned short*)take((size_t)N * 128 * 2);
  unsigned short* aggb  = (unsigned short*)take((size_t)N * 128 * 2);
  unsigned short* zb    = (unsigned short*)take((size_t)N * 128 * 2);
  unsigned short* agg2z = (unsigned short*)take((size_t)N * 128 * 2);
  unsigned short* w1aT  = (unsigned short*)take(128 * 128 * 2);
  unsigned short* w1bT  = (unsigned short*)take(128 * 128 * 2);
  unsigned short* w2aT  = (unsigned short*)take(64 * 128 * 2);
  unsigned short* w2bT  = (unsigned short*)take(64 * 128 * 2);
  unsigned short* wf1T  = (unsigned short*)take(128 * 128 * 2);
  unsigned short* wf2T  = (unsigned short*)take(128 * 128 * 2);

  const int gatherBlocks = (N + 3) / 4;
  const int mtiles = (N + 63) / 64;
  const int n4 = (N * 128) / 4;
  const int featB = (n4 + 255) / 256;
  const int scanL = (L + 1023) / 1024;

  // A) per-block bucket histograms (no global atomics, no memsets)
  bucket_hist<<<NBLK, 256, 0, stream>>>(src, dst, blk_cnt, E, nbk);
  // B) exclusive scan of concatenated counts -> absolute write offsets
  scan_partial_g<<<scanL, 256, 0, stream>>>(blk_cnt, part, L);
  scan_final_g<<<scanL, 256, 0, stream>>>(blk_cnt, part, boff, L);
  // C) bucket-partition edges (LDS cursors only)
  bucket_scatter<<<NBLK, 256, 0, stream>>>(src, dst, boff, pairs, E, nbk);
  // D) degrees + row_off + CSR fill (self-contained per block -> no cross-block race)
  bucket_finish<<<2 * nbk, 256, 0, stream>>>(
      pairs, boff, row_off, deg_d, deg_s, csr_src, N, E, nbk);
  // E) converts in their OWN dispatch (featb reads deg_s produced by D)
  convert_all<<<featB + 6, 256, 0, stream>>>(
      features, deg_s, featb, n4,
      W1a, W1b, W2a, W2b, Wf1, Wf2,
      w1aT, w1bT, w2aT, w2bT, wf1T, wf2T);
  // first aggregation (dedicated gather, high occupancy)
  gather128b<<<gatherBlocks, 256, 0, stream>>>(row_off, csr_src, featb, aggb, N);
  // z = [h1a@W2a | h1b@W2b]  (branch-parallel, W1^T staged in LDS)
  gemm_mid_lds<<<dim3(mtiles, 2), 256, 0, stream>>>(aggb, w1aT, b1a, w1bT, b1b,
                                                    w2aT, w2bT, deg_s, deg_d, zb, N);
  // second aggregation over z
  gather128b<<<gatherBlocks, 256, 0, stream>>>(row_off, csr_src, zb, agg2z, N);
  // tail: scale+bias -> LN+resid -> FFN1 -> FFN2 -> out (FFN weights in LDS)
  fused_tail5<<<mtiles, 256, 0, stream>>>(agg2z, featb, b2a, b2b,
                                          deg_s, deg_d, ln_g, ln_b,
                                          wf1T, bf1, wf2T, bf2, out, N);
}